// Round 1
// baseline (2669.063 us; speedup 1.0000x reference)
//
#include <hip/hip_runtime.h>

#define B_ 16
#define CN_ 22
#define T_ 1000
#define EXP_ 300
#define FCH_ 150
#define SPD_ 100

// workspace layout (bytes)
static constexpr unsigned long long OFF_M2   = 0ull;                       // 3*150*22 f32
static constexpr unsigned long long OFF_HCAT = 65536ull;                   // 16*450*1000 f32
static constexpr unsigned long long OFF_XC   = OFF_HCAT + 28800000ull;     // 16*100*1000 f32
static constexpr unsigned long long OFF_COV  = OFF_XC   + 6400000ull;      // 16*100*100 f32
static constexpr unsigned long long OFF_T1   = OFF_COV  + 640000ull;       // 16*100*100 f32
static constexpr unsigned long long OFF_P    = OFF_T1   + 640000ull;       // 16*100*100 f32
// total ~37.2 MB

struct PrepPtrs  { const float* w1[3]; const float* w2[3]; const float* w3[3]; const float* w4[3]; };
struct FrontPtrs { const float* g1[3]; const float* b1[3]; const float* w5[3];
                   const float* g2[3]; const float* b2[3]; int K[3]; };

__device__ __forceinline__ float block_sum(float v, float* sbuf) {
  #pragma unroll
  for (int off = 32; off > 0; off >>= 1) v += __shfl_down(v, off, 64);
  const int wid  = threadIdx.x >> 6;
  const int lane = threadIdx.x & 63;
  const int nw   = blockDim.x >> 6;
  if (lane == 0) sbuf[wid] = v;
  __syncthreads();
  float r = 0.f;
  for (int w = 0; w < nw; ++w) r += sbuf[w];
  __syncthreads();
  return r;
}

// ---------------------------------------------------------------------------
// K1: fold conv(3,1) + w2-expand + max-norm depthwise spatial + pointwise into
// M2[beta][o][c] (150x22 per block).
// ---------------------------------------------------------------------------
__global__ __launch_bounds__(256) void k_prep(PrepPtrs pp, float* __restrict__ M2) {
  const int beta = blockIdx.x;
  __shared__ float w3r[EXP_*CN_];   // w2-folded constrained weights
  __shared__ float M[FCH_*CN_];
  const float* w1 = pp.w1[beta];
  const float* w2 = pp.w2[beta];
  const float* w3 = pp.w3[beta];
  const float* w4 = pp.w4[beta];

  for (int g = threadIdx.x; g < EXP_; g += 256) {
    float s = 0.f;
    for (int c = 0; c < CN_; ++c) { float w = w3[g*CN_ + c]; s += w*w; }
    float n = sqrtf(s);
    float scale = fminf(1.f, 1.f/(n + 1e-12f)) * w2[g];
    for (int c = 0; c < CN_; ++c) w3r[g*CN_ + c] = w3[g*CN_ + c] * scale;
  }
  __syncthreads();
  for (int idx = threadIdx.x; idx < FCH_*CN_; idx += 256) {
    int o = idx / CN_, c = idx - o*CN_;
    float acc = 0.f;
    for (int g = 0; g < EXP_; ++g) acc += w4[o*EXP_ + g] * w3r[g*CN_ + c];
    M[idx] = acc;
  }
  __syncthreads();
  const float k0 = w1[0], k1 = w1[1], k2 = w1[2];
  for (int idx = threadIdx.x; idx < FCH_*CN_; idx += 256) {
    int c = idx % CN_;
    float v = k1 * M[idx];
    if (c > 0)       v += k2 * M[idx - 1];
    if (c < CN_ - 1) v += k0 * M[idx + 1];
    M2[beta*FCH_*CN_ + idx] = v;
  }
}

// ---------------------------------------------------------------------------
// K2: per (beta,b,o) row: h = M2 row @ x[b]  -> LN(g1,b1) -> depthwise conv K
//     (same pad) -> LN(g2,b2) -> hcat[b, beta*150+o, :]
// ---------------------------------------------------------------------------
__global__ __launch_bounds__(256) void k_front(const float* __restrict__ x,
                                               const float* __restrict__ M2,
                                               FrontPtrs fp,
                                               float* __restrict__ hcat) {
  const int wg   = blockIdx.x;
  const int beta = wg / (B_*FCH_);
  const int rem  = wg - beta*(B_*FCH_);
  const int b    = rem / FCH_;
  const int o    = rem - b*FCH_;
  const int K    = fp.K[beta];
  const int Kh   = K >> 1;

  __shared__ float m2[CN_];
  __shared__ float hb2[T_];
  __shared__ float w5s[80];
  __shared__ float red[8];

  if (threadIdx.x < CN_) m2[threadIdx.x] = M2[(beta*FCH_ + o)*CN_ + threadIdx.x];
  if (threadIdx.x < K)   w5s[threadIdx.x] = fp.w5[beta][o*K + threadIdx.x];
  __syncthreads();

  const float* xb = x + (size_t)b*CN_*T_;
  float hv[4];
  float psum = 0.f;
  #pragma unroll
  for (int e = 0; e < 4; ++e) {
    int t = threadIdx.x + 256*e;
    float acc = 0.f;
    if (t < T_) {
      #pragma unroll
      for (int c = 0; c < CN_; ++c) acc += m2[c] * xb[c*T_ + t];
    }
    hv[e] = acc; psum += acc;
  }
  float mean = block_sum(psum, red) * (1.f/T_);
  float pv = 0.f;
  #pragma unroll
  for (int e = 0; e < 4; ++e) { int t = threadIdx.x + 256*e; if (t < T_) { float d = hv[e]-mean; pv += d*d; } }
  float var = block_sum(pv, red) * (1.f/T_);
  float inv = rsqrtf(var + 1e-5f);
  const float* g1 = fp.g1[beta]; const float* b1 = fp.b1[beta];
  #pragma unroll
  for (int e = 0; e < 4; ++e) { int t = threadIdx.x + 256*e; if (t < T_) hb2[t] = (hv[e]-mean)*inv*g1[t] + b1[t]; }
  __syncthreads();

  float cv[4];
  float ps2 = 0.f;
  #pragma unroll
  for (int e = 0; e < 4; ++e) {
    int t = threadIdx.x + 256*e;
    float acc = 0.f;
    if (t < T_) {
      int lo = t - Kh;
      for (int k = 0; k < K; ++k) {
        int tt = lo + k;
        float hvv = (tt >= 0 && tt < T_) ? hb2[tt] : 0.f;
        acc += hvv * w5s[k];
      }
    }
    cv[e] = acc; ps2 += acc;
  }
  float mean2 = block_sum(ps2, red) * (1.f/T_);
  float pv2 = 0.f;
  #pragma unroll
  for (int e = 0; e < 4; ++e) { int t = threadIdx.x + 256*e; if (t < T_) { float d = cv[e]-mean2; pv2 += d*d; } }
  float var2 = block_sum(pv2, red) * (1.f/T_);
  float inv2 = rsqrtf(var2 + 1e-5f);
  const float* g2 = fp.g2[beta]; const float* b2 = fp.b2[beta];
  float* hrow = hcat + ((size_t)b*(3*FCH_) + beta*FCH_ + o)*T_;
  #pragma unroll
  for (int e = 0; e < 4; ++e) { int t = threadIdx.x + 256*e; if (t < T_) hrow[t] = (cv[e]-mean2)*inv2*g2[t] + b2[t]; }
}

// ---------------------------------------------------------------------------
// K3: h_s = w_sconv @ hcat per b (100x450 @ 450x1000), subtract per-row time
//     mean, store xc. One wg per (b, 10-row s-tile).
// ---------------------------------------------------------------------------
__global__ __launch_bounds__(256) void k_sconv(const float* __restrict__ hcat,
                                               const float* __restrict__ wsc,
                                               float* __restrict__ xc) {
  const int b  = blockIdx.x / 10;
  const int s0 = (blockIdx.x % 10) * 10;
  __shared__ float ws[10*450];
  __shared__ float red[8];
  for (int idx = threadIdx.x; idx < 4500; idx += 256) {
    int s = idx / 450, i = idx - s*450;
    ws[idx] = wsc[(s0+s)*450 + i];
  }
  __syncthreads();
  float acc[10][4];
  #pragma unroll
  for (int s = 0; s < 10; ++s)
    #pragma unroll
    for (int e = 0; e < 4; ++e) acc[s][e] = 0.f;
  const float* hb = hcat + (size_t)b*450*T_;
  for (int i = 0; i < 450; ++i) {
    float xv[4];
    #pragma unroll
    for (int e = 0; e < 4; ++e) { int t = threadIdx.x + 256*e; xv[e] = (t < T_) ? hb[(size_t)i*T_ + t] : 0.f; }
    #pragma unroll
    for (int s = 0; s < 10; ++s) {
      float w = ws[s*450 + i];
      #pragma unroll
      for (int e = 0; e < 4; ++e) acc[s][e] += w * xv[e];
    }
  }
  for (int s = 0; s < 10; ++s) {
    float mu = block_sum(acc[s][0]+acc[s][1]+acc[s][2]+acc[s][3], red) * (1.f/T_);
    float* xr = xc + ((size_t)b*SPD_ + s0 + s)*T_;
    #pragma unroll
    for (int e = 0; e < 4; ++e) { int t = threadIdx.x + 256*e; if (t < T_) xr[t] = acc[s][e] - mu; }
  }
}

// ---------------------------------------------------------------------------
// K4a: cov = xc xc^T /999 + 1e-4 I (fp64 accum across chunks, fp32 within)
// wg = (b, 20-wide j-tile); thread = 4x2 strided register tile.
// ---------------------------------------------------------------------------
__global__ __launch_bounds__(256) void k_cov(const float* __restrict__ xc, float* __restrict__ cov) {
  const int b  = blockIdx.x / 5;
  const int j0 = (blockIdx.x % 5) * 20;
  __shared__ __align__(16) float xst[SPD_*100];
  const int it = threadIdx.x / 10;
  const int jj = threadIdx.x - it*10;
  const bool act = threadIdx.x < 250;
  double a64[4][2] = {{0.0,0.0},{0.0,0.0},{0.0,0.0},{0.0,0.0}};
  for (int ch = 0; ch < 10; ++ch) {
    __syncthreads();
    const int tc0 = ch*100;
    for (int idx = threadIdx.x; idx < SPD_*100; idx += 256) {
      int row = idx / 100, tt = idx - row*100;
      xst[idx] = xc[((size_t)b*SPD_ + row)*T_ + tc0 + tt];
    }
    __syncthreads();
    if (act) {
      float a32[4][2] = {{0,0},{0,0},{0,0},{0,0}};
      for (int t4 = 0; t4 < 100; t4 += 4) {
        float4 xi[4], xj[2];
        #pragma unroll
        for (int r = 0; r < 4; ++r) xi[r] = *(const float4*)&xst[(it + 25*r)*100 + t4];
        #pragma unroll
        for (int s = 0; s < 2; ++s) xj[s] = *(const float4*)&xst[(j0 + jj + 10*s)*100 + t4];
        #pragma unroll
        for (int r = 0; r < 4; ++r)
          #pragma unroll
          for (int s = 0; s < 2; ++s)
            a32[r][s] += xi[r].x*xj[s].x + xi[r].y*xj[s].y + xi[r].z*xj[s].z + xi[r].w*xj[s].w;
      }
      #pragma unroll
      for (int r = 0; r < 4; ++r)
        #pragma unroll
        for (int s = 0; s < 2; ++s) a64[r][s] += (double)a32[r][s];
    }
  }
  if (act) {
    #pragma unroll
    for (int r = 0; r < 4; ++r) {
      #pragma unroll
      for (int s = 0; s < 2; ++s) {
        int i = it + 25*r, j = j0 + jj + 10*s;
        double v = a64[r][s] * (1.0/999.0);
        if (i == j) v += 1e-4;
        cov[(size_t)b*SPD_*SPD_ + i*SPD_ + j] = (float)v;
      }
    }
  }
}

// ---------------------------------------------------------------------------
// K4b: T1 = C @ W^T   (fp64 accumulate over fp32 operands)
// ---------------------------------------------------------------------------
__global__ __launch_bounds__(256) void k_aff1(const float* __restrict__ cov,
                                              const float* __restrict__ waff,
                                              float* __restrict__ T1) {
  const int b  = blockIdx.x / 5;
  const int j0 = (blockIdx.x % 5) * 20;
  __shared__ float Cs[SPD_*101];
  __shared__ float Ws[20*100];
  for (int idx = threadIdx.x; idx < SPD_*SPD_; idx += 256) {
    int r = idx / 100, c = idx - r*100;
    Cs[r*101 + c] = cov[(size_t)b*SPD_*SPD_ + idx];
  }
  for (int idx = threadIdx.x; idx < 2000; idx += 256) {
    int jl = idx / 100, k = idx - jl*100;
    Ws[idx] = waff[(j0+jl)*100 + k];
  }
  __syncthreads();
  if (threadIdx.x < 250) {
    const int it = threadIdx.x / 10, jj = threadIdx.x % 10;
    double acc[4][2] = {{0.0,0.0},{0.0,0.0},{0.0,0.0},{0.0,0.0}};
    for (int k = 0; k < 100; ++k) {
      double cvv[4], wv[2];
      #pragma unroll
      for (int r = 0; r < 4; ++r) cvv[r] = (double)Cs[(it + 25*r)*101 + k];
      #pragma unroll
      for (int s = 0; s < 2; ++s) wv[s] = (double)Ws[(jj + 10*s)*100 + k];
      #pragma unroll
      for (int r = 0; r < 4; ++r)
        #pragma unroll
        for (int s = 0; s < 2; ++s) acc[r][s] += cvv[r]*wv[s];
    }
    #pragma unroll
    for (int r = 0; r < 4; ++r)
      #pragma unroll
      for (int s = 0; s < 2; ++s)
        T1[(size_t)b*SPD_*SPD_ + (it + 25*r)*100 + (j0 + jj + 10*s)] = (float)acc[r][s];
  }
}

// ---------------------------------------------------------------------------
// K4c: P = W @ T1
// ---------------------------------------------------------------------------
__global__ __launch_bounds__(256) void k_aff2(const float* __restrict__ T1,
                                              const float* __restrict__ waff,
                                              float* __restrict__ P) {
  const int b  = blockIdx.x / 5;
  const int j0 = (blockIdx.x % 5) * 20;
  __shared__ float T1s[100*20];
  for (int idx = threadIdx.x; idx < 2000; idx += 256) {
    int k = idx / 20, jl = idx - k*20;
    T1s[idx] = T1[(size_t)b*SPD_*SPD_ + k*100 + j0 + jl];
  }
  __syncthreads();
  if (threadIdx.x < 250) {
    const int it = threadIdx.x / 10, jj = threadIdx.x % 10;
    double acc[4][2] = {{0.0,0.0},{0.0,0.0},{0.0,0.0},{0.0,0.0}};
    for (int k = 0; k < 100; ++k) {
      double wv[4], tv[2];
      #pragma unroll
      for (int r = 0; r < 4; ++r) wv[r] = (double)waff[(it + 25*r)*100 + k];
      #pragma unroll
      for (int s = 0; s < 2; ++s) tv[s] = (double)T1s[k*20 + jj + 10*s];
      #pragma unroll
      for (int r = 0; r < 4; ++r)
        #pragma unroll
        for (int s = 0; s < 2; ++s) acc[r][s] += wv[r]*tv[s];
    }
    #pragma unroll
    for (int r = 0; r < 4; ++r)
      #pragma unroll
      for (int s = 0; s < 2; ++s)
        P[(size_t)b*SPD_*SPD_ + (it + 25*r)*100 + (j0 + jj + 10*s)] = (float)acc[r][s];
  }
}

// ---------------------------------------------------------------------------
// K5: one-sided Jacobi eig of symmetric PSD P (100x100) per block b, then
// L = sum_c log(clip(lam))/lam^2 * g_c g_c^T, write scaled upper-tri flat.
// G columns in LDS fp32; dots/rotations fp64; tournament round-robin.
// ---------------------------------------------------------------------------
__global__ __launch_bounds__(832) void k_eig(const float* __restrict__ P, float* __restrict__ out) {
  __shared__ __align__(16) float G[SPD_*SPD_];
  __shared__ double dn[SPD_];
  __shared__ double wc[SPD_];
  __shared__ int flag;
  const int tid = threadIdx.x;
  const int b = blockIdx.x;

  for (int idx = tid; idx < SPD_*SPD_; idx += 832) G[idx] = P[b*SPD_*SPD_ + idx];
  if (tid == 0) flag = 0;
  __syncthreads();
  if (tid < SPD_) {
    const float* col = &G[tid*SPD_];
    double s = 0.0;
    for (int i = 0; i < SPD_; ++i) { double v = (double)col[i]; s += v*v; }
    dn[tid] = s;
  }
  __syncthreads();

  const int g = tid >> 4;
  const int l = tid & 15;
  const bool act = (g < 50);

  for (int sweep = 0; sweep < 14; ++sweep) {
    for (int r = 0; r < 99; ++r) {
      int p, q;
      if (g == 0) {
        p = 99;
        q = r + 98; if (q >= 99) q -= 99;
      } else {
        p = r + g - 1;  if (p >= 99) p -= 99;
        q = r + 98 - g; if (q >= 99) q -= 99;
      }
      float4 p0, p1, q0, q1;
      p0 = p1 = q0 = q1 = make_float4(0.f,0.f,0.f,0.f);
      double gamma = 0.0;
      if (act) {
        const float4* cp = (const float4*)&G[p*SPD_];
        const float4* cq = (const float4*)&G[q*SPD_];
        p0 = cp[l]; q0 = cq[l];
        gamma = (double)p0.x*(double)q0.x + (double)p0.y*(double)q0.y
              + (double)p0.z*(double)q0.z + (double)p0.w*(double)q0.w;
        if (l < 9) {
          p1 = cp[16+l]; q1 = cq[16+l];
          gamma += (double)p1.x*(double)q1.x + (double)p1.y*(double)q1.y
                 + (double)p1.z*(double)q1.z + (double)p1.w*(double)q1.w;
        }
      }
      gamma += __shfl_down(gamma, 8, 16);
      gamma += __shfl_down(gamma, 4, 16);
      gamma += __shfl_down(gamma, 2, 16);
      gamma += __shfl_down(gamma, 1, 16);
      double cr = 1.0, sr = 0.0;
      int rot = 0;
      if (act && l == 0) {
        double alpha = dn[p], beta = dn[q];
        double g2 = gamma * gamma;
        if (g2 > 1e-16 * alpha * beta) {         // rotate threshold |g| > 1e-8*sqrt(ab)
          rot = 1;
          if (g2 > 1e-14 * alpha * beta) flag = 1; // convergence threshold 1e-7
          double tau = (beta - alpha) / (2.0 * gamma);
          double t = ((tau >= 0.0) ? 1.0 : -1.0) / (fabs(tau) + sqrt(1.0 + tau*tau));
          cr = 1.0 / sqrt(1.0 + t*t);
          sr = t * cr;
          dn[p] = alpha - t*gamma;
          dn[q] = beta  + t*gamma;
        }
      }
      rot = __shfl(rot, 0, 16);
      cr  = __shfl(cr, 0, 16);
      sr  = __shfl(sr, 0, 16);
      if (act && rot) {
        float4* cp = (float4*)&G[p*SPD_];
        float4* cq = (float4*)&G[q*SPD_];
        float4 a, bb;
        a.x  = (float)(cr*(double)p0.x - sr*(double)q0.x);
        a.y  = (float)(cr*(double)p0.y - sr*(double)q0.y);
        a.z  = (float)(cr*(double)p0.z - sr*(double)q0.z);
        a.w  = (float)(cr*(double)p0.w - sr*(double)q0.w);
        bb.x = (float)(sr*(double)p0.x + cr*(double)q0.x);
        bb.y = (float)(sr*(double)p0.y + cr*(double)q0.y);
        bb.z = (float)(sr*(double)p0.z + cr*(double)q0.z);
        bb.w = (float)(sr*(double)p0.w + cr*(double)q0.w);
        cp[l] = a; cq[l] = bb;
        if (l < 9) {
          float4 a2, b2;
          a2.x  = (float)(cr*(double)p1.x - sr*(double)q1.x);
          a2.y  = (float)(cr*(double)p1.y - sr*(double)q1.y);
          a2.z  = (float)(cr*(double)p1.z - sr*(double)q1.z);
          a2.w  = (float)(cr*(double)p1.w - sr*(double)q1.w);
          b2.x  = (float)(sr*(double)p1.x + cr*(double)q1.x);
          b2.y  = (float)(sr*(double)p1.y + cr*(double)q1.y);
          b2.z  = (float)(sr*(double)p1.z + cr*(double)q1.z);
          b2.w  = (float)(sr*(double)p1.w + cr*(double)q1.w);
          cp[16+l] = a2; cq[16+l] = b2;
        }
      }
      __syncthreads();
    }
    int f = flag;
    __syncthreads();
    if (f == 0) break;
    if (tid == 0) flag = 0;
    __syncthreads();
  }

  // eigenvalues from fresh column norms; wc = log(clip(lam,1e-6)) / lam^2
  if (tid < SPD_) {
    const float* col = &G[tid*SPD_];
    double s = 0.0;
    for (int i = 0; i < SPD_; ++i) { double v = (double)col[i]; s += v*v; }
    double lam = sqrt(s);
    double lc  = (lam < 1e-6) ? 1e-6 : lam;
    wc[tid] = log(lc) / ((s > 1e-300) ? s : 1e-300);
  }
  __syncthreads();

  // L = sum_c wc[c] * g_c g_c^T ; write scaled upper-tri flat to out[64 + b*5050 + idx]
  if (tid < 625) {
    const int ti = (tid / 25) * 4;
    const int tj = (tid % 25) * 4;
    double acc[4][4];
    #pragma unroll
    for (int r = 0; r < 4; ++r)
      #pragma unroll
      for (int s = 0; s < 4; ++s) acc[r][s] = 0.0;
    for (int c = 0; c < SPD_; ++c) {
      const float* col = &G[c*SPD_];
      float4 ga = *(const float4*)&col[ti];
      float4 gb = *(const float4*)&col[tj];
      double w = wc[c];
      double wa[4] = { w*(double)ga.x, w*(double)ga.y, w*(double)ga.z, w*(double)ga.w };
      double bv[4] = { (double)gb.x, (double)gb.y, (double)gb.z, (double)gb.w };
      #pragma unroll
      for (int r = 0; r < 4; ++r)
        #pragma unroll
        for (int s = 0; s < 4; ++s) acc[r][s] += wa[r]*bv[s];
    }
    const double RT2 = 1.4142135623730950488;
    #pragma unroll
    for (int r = 0; r < 4; ++r) {
      #pragma unroll
      for (int s = 0; s < 4; ++s) {
        int i = ti + r, j = tj + s;
        if (i <= j) {
          int idx = i*SPD_ - (i*(i+1))/2 + j;
          out[64 + b*5050 + idx] = (float)(acc[r][s] * (i == j ? 1.0 : RT2));
        }
      }
    }
  }
}

// ---------------------------------------------------------------------------
// K6: logits = flat @ w_fc^T + b_fc
// ---------------------------------------------------------------------------
__global__ __launch_bounds__(256) void k_fc(const float* __restrict__ wfc,
                                            const float* __restrict__ bfc,
                                            float* __restrict__ out) {
  __shared__ float red[8];
  const int b = blockIdx.x;
  const float* flat = out + 64 + b*5050;
  float a0 = 0.f, a1 = 0.f, a2 = 0.f, a3 = 0.f;
  for (int k = threadIdx.x; k < 5050; k += 256) {
    float f = flat[k];
    a0 += f * wfc[k];
    a1 += f * wfc[5050 + k];
    a2 += f * wfc[10100 + k];
    a3 += f * wfc[15150 + k];
  }
  a0 = block_sum(a0, red);
  a1 = block_sum(a1, red);
  a2 = block_sum(a2, red);
  a3 = block_sum(a3, red);
  if (threadIdx.x == 0) {
    out[b*4 + 0] = a0 + bfc[0];
    out[b*4 + 1] = a1 + bfc[1];
    out[b*4 + 2] = a2 + bfc[2];
    out[b*4 + 3] = a3 + bfc[3];
  }
}

extern "C" void kernel_launch(void* const* d_in, const int* in_sizes, int n_in,
                              void* d_out, int out_size, void* d_ws, size_t ws_size,
                              hipStream_t stream) {
  (void)in_sizes; (void)n_in; (void)out_size; (void)ws_size;
  const float* x = (const float*)d_in[0];
  const float* bw[3][9];
  for (int i = 0; i < 3; ++i)
    for (int j = 0; j < 9; ++j)
      bw[i][j] = (const float*)d_in[1 + i*9 + j];   // w1,w2,w3,w4,g1,b1,w5,g2,b2
  const float* w_sconv = (const float*)d_in[28];
  const float* w_aff   = (const float*)d_in[29];
  const float* w_fc    = (const float*)d_in[30];
  const float* b_fc    = (const float*)d_in[31];

  char* ws = (char*)d_ws;
  float* M2   = (float*)(ws + OFF_M2);
  float* hcat = (float*)(ws + OFF_HCAT);
  float* xc   = (float*)(ws + OFF_XC);
  float* cov  = (float*)(ws + OFF_COV);
  float* T1   = (float*)(ws + OFF_T1);
  float* P    = (float*)(ws + OFF_P);
  float* out  = (float*)d_out;

  PrepPtrs pp; FrontPtrs fp;
  for (int i = 0; i < 3; ++i) {
    pp.w1[i] = bw[i][0]; pp.w2[i] = bw[i][1]; pp.w3[i] = bw[i][2]; pp.w4[i] = bw[i][3];
    fp.g1[i] = bw[i][4]; fp.b1[i] = bw[i][5]; fp.w5[i] = bw[i][6];
    fp.g2[i] = bw[i][7]; fp.b2[i] = bw[i][8];
  }
  fp.K[0] = 15; fp.K[1] = 75; fp.K[2] = 55;

  hipLaunchKernelGGL(k_prep,  dim3(3),            dim3(256), 0, stream, pp, M2);
  hipLaunchKernelGGL(k_front, dim3(3*B_*FCH_),    dim3(256), 0, stream, x, M2, fp, hcat);
  hipLaunchKernelGGL(k_sconv, dim3(B_*10),        dim3(256), 0, stream, hcat, w_sconv, xc);
  hipLaunchKernelGGL(k_cov,   dim3(B_*5),         dim3(256), 0, stream, xc, cov);
  hipLaunchKernelGGL(k_aff1,  dim3(B_*5),         dim3(256), 0, stream, cov, w_aff, T1);
  hipLaunchKernelGGL(k_aff2,  dim3(B_*5),         dim3(256), 0, stream, T1, w_aff, P);
  hipLaunchKernelGGL(k_eig,   dim3(B_),           dim3(832), 0, stream, P, out);
  hipLaunchKernelGGL(k_fc,    dim3(B_),           dim3(256), 0, stream, w_fc, b_fc, out);
}

// Round 2
// 1831.949 us; speedup vs baseline: 1.4570x; 1.4570x over previous
//
#include <hip/hip_runtime.h>

#define B_ 16
#define CN_ 22
#define T_ 1000
#define EXP_ 300
#define FCH_ 150
#define SPD_ 100
#define LDSTR 108   // column stride in floats: 12 mod 32 -> walks all bank quads; /4 ok

// workspace layout (bytes)
static constexpr unsigned long long OFF_M2   = 0ull;                       // 3*150*22 f32
static constexpr unsigned long long OFF_HCAT = 65536ull;                   // 16*450*1000 f32
static constexpr unsigned long long OFF_XC   = OFF_HCAT + 28800000ull;     // 16*100*1000 f32
static constexpr unsigned long long OFF_COV  = OFF_XC   + 6400000ull;      // 16*100*100 f32
static constexpr unsigned long long OFF_T1   = OFF_COV  + 640000ull;       // 16*100*100 f32
static constexpr unsigned long long OFF_P    = OFF_T1   + 640000ull;       // 16*100*100 f32

struct PrepPtrs  { const float* w1[3]; const float* w2[3]; const float* w3[3]; const float* w4[3]; };
struct FrontPtrs { const float* g1[3]; const float* b1[3]; const float* w5[3];
                   const float* g2[3]; const float* b2[3]; int K[3]; };

__device__ __forceinline__ float block_sum(float v, float* sbuf) {
  #pragma unroll
  for (int off = 32; off > 0; off >>= 1) v += __shfl_down(v, off, 64);
  const int wid  = threadIdx.x >> 6;
  const int lane = threadIdx.x & 63;
  const int nw   = blockDim.x >> 6;
  if (lane == 0) sbuf[wid] = v;
  __syncthreads();
  float r = 0.f;
  for (int w = 0; w < nw; ++w) r += sbuf[w];
  __syncthreads();
  return r;
}

// ---------------------------------------------------------------------------
// K1: fold conv(3,1) + w2-expand + max-norm depthwise spatial + pointwise into
// M2[beta][o][c] (150x22 per block).
// ---------------------------------------------------------------------------
__global__ __launch_bounds__(256) void k_prep(PrepPtrs pp, float* __restrict__ M2) {
  const int beta = blockIdx.x;
  __shared__ float w3r[EXP_*CN_];
  __shared__ float M[FCH_*CN_];
  const float* w1 = pp.w1[beta];
  const float* w2 = pp.w2[beta];
  const float* w3 = pp.w3[beta];
  const float* w4 = pp.w4[beta];

  for (int g = threadIdx.x; g < EXP_; g += 256) {
    float s = 0.f;
    for (int c = 0; c < CN_; ++c) { float w = w3[g*CN_ + c]; s += w*w; }
    float n = sqrtf(s);
    float scale = fminf(1.f, 1.f/(n + 1e-12f)) * w2[g];
    for (int c = 0; c < CN_; ++c) w3r[g*CN_ + c] = w3[g*CN_ + c] * scale;
  }
  __syncthreads();
  for (int idx = threadIdx.x; idx < FCH_*CN_; idx += 256) {
    int o = idx / CN_, c = idx - o*CN_;
    float acc = 0.f;
    for (int g = 0; g < EXP_; ++g) acc += w4[o*EXP_ + g] * w3r[g*CN_ + c];
    M[idx] = acc;
  }
  __syncthreads();
  const float k0 = w1[0], k1 = w1[1], k2 = w1[2];
  for (int idx = threadIdx.x; idx < FCH_*CN_; idx += 256) {
    int c = idx % CN_;
    float v = k1 * M[idx];
    if (c > 0)       v += k2 * M[idx - 1];
    if (c < CN_ - 1) v += k0 * M[idx + 1];
    M2[beta*FCH_*CN_ + idx] = v;
  }
}

// ---------------------------------------------------------------------------
// K2: per (beta,b,o) row: h = M2 row @ x[b] -> LN -> depthwise conv K -> LN
// ---------------------------------------------------------------------------
__global__ __launch_bounds__(256) void k_front(const float* __restrict__ x,
                                               const float* __restrict__ M2,
                                               FrontPtrs fp,
                                               float* __restrict__ hcat) {
  const int wg   = blockIdx.x;
  const int beta = wg / (B_*FCH_);
  const int rem  = wg - beta*(B_*FCH_);
  const int b    = rem / FCH_;
  const int o    = rem - b*FCH_;
  const int K    = fp.K[beta];
  const int Kh   = K >> 1;

  __shared__ float m2[CN_];
  __shared__ float hb2[T_];
  __shared__ float w5s[80];
  __shared__ float red[8];

  if (threadIdx.x < CN_) m2[threadIdx.x] = M2[(beta*FCH_ + o)*CN_ + threadIdx.x];
  if (threadIdx.x < K)   w5s[threadIdx.x] = fp.w5[beta][o*K + threadIdx.x];
  __syncthreads();

  const float* xb = x + (size_t)b*CN_*T_;
  float hv[4];
  float psum = 0.f;
  #pragma unroll
  for (int e = 0; e < 4; ++e) {
    int t = threadIdx.x + 256*e;
    float acc = 0.f;
    if (t < T_) {
      #pragma unroll
      for (int c = 0; c < CN_; ++c) acc += m2[c] * xb[c*T_ + t];
    }
    hv[e] = acc; psum += acc;
  }
  float mean = block_sum(psum, red) * (1.f/T_);
  float pv = 0.f;
  #pragma unroll
  for (int e = 0; e < 4; ++e) { int t = threadIdx.x + 256*e; if (t < T_) { float d = hv[e]-mean; pv += d*d; } }
  float var = block_sum(pv, red) * (1.f/T_);
  float inv = rsqrtf(var + 1e-5f);
  const float* g1 = fp.g1[beta]; const float* b1 = fp.b1[beta];
  #pragma unroll
  for (int e = 0; e < 4; ++e) { int t = threadIdx.x + 256*e; if (t < T_) hb2[t] = (hv[e]-mean)*inv*g1[t] + b1[t]; }
  __syncthreads();

  float cv[4];
  float ps2 = 0.f;
  #pragma unroll
  for (int e = 0; e < 4; ++e) {
    int t = threadIdx.x + 256*e;
    float acc = 0.f;
    if (t < T_) {
      int lo = t - Kh;
      for (int k = 0; k < K; ++k) {
        int tt = lo + k;
        float hvv = (tt >= 0 && tt < T_) ? hb2[tt] : 0.f;
        acc += hvv * w5s[k];
      }
    }
    cv[e] = acc; ps2 += acc;
  }
  float mean2 = block_sum(ps2, red) * (1.f/T_);
  float pv2 = 0.f;
  #pragma unroll
  for (int e = 0; e < 4; ++e) { int t = threadIdx.x + 256*e; if (t < T_) { float d = cv[e]-mean2; pv2 += d*d; } }
  float var2 = block_sum(pv2, red) * (1.f/T_);
  float inv2 = rsqrtf(var2 + 1e-5f);
  const float* g2 = fp.g2[beta]; const float* b2 = fp.b2[beta];
  float* hrow = hcat + ((size_t)b*(3*FCH_) + beta*FCH_ + o)*T_;
  #pragma unroll
  for (int e = 0; e < 4; ++e) { int t = threadIdx.x + 256*e; if (t < T_) hrow[t] = (cv[e]-mean2)*inv2*g2[t] + b2[t]; }
}

// ---------------------------------------------------------------------------
// K3: h_s = w_sconv @ hcat per b, subtract per-row time mean, store xc.
// ---------------------------------------------------------------------------
__global__ __launch_bounds__(256) void k_sconv(const float* __restrict__ hcat,
                                               const float* __restrict__ wsc,
                                               float* __restrict__ xc) {
  const int b  = blockIdx.x / 10;
  const int s0 = (blockIdx.x % 10) * 10;
  __shared__ float ws[10*450];
  __shared__ float red[8];
  for (int idx = threadIdx.x; idx < 4500; idx += 256) {
    int s = idx / 450, i = idx - s*450;
    ws[idx] = wsc[(s0+s)*450 + i];
  }
  __syncthreads();
  float acc[10][4];
  #pragma unroll
  for (int s = 0; s < 10; ++s)
    #pragma unroll
    for (int e = 0; e < 4; ++e) acc[s][e] = 0.f;
  const float* hb = hcat + (size_t)b*450*T_;
  for (int i = 0; i < 450; ++i) {
    float xv[4];
    #pragma unroll
    for (int e = 0; e < 4; ++e) { int t = threadIdx.x + 256*e; xv[e] = (t < T_) ? hb[(size_t)i*T_ + t] : 0.f; }
    #pragma unroll
    for (int s = 0; s < 10; ++s) {
      float w = ws[s*450 + i];
      #pragma unroll
      for (int e = 0; e < 4; ++e) acc[s][e] += w * xv[e];
    }
  }
  for (int s = 0; s < 10; ++s) {
    float mu = block_sum(acc[s][0]+acc[s][1]+acc[s][2]+acc[s][3], red) * (1.f/T_);
    float* xr = xc + ((size_t)b*SPD_ + s0 + s)*T_;
    #pragma unroll
    for (int e = 0; e < 4; ++e) { int t = threadIdx.x + 256*e; if (t < T_) xr[t] = acc[s][e] - mu; }
  }
}

// ---------------------------------------------------------------------------
// K4a: cov = xc xc^T /999 + 1e-4 I (fp64 accum across chunks)
// ---------------------------------------------------------------------------
__global__ __launch_bounds__(256) void k_cov(const float* __restrict__ xc, float* __restrict__ cov) {
  const int b  = blockIdx.x / 5;
  const int j0 = (blockIdx.x % 5) * 20;
  __shared__ __align__(16) float xst[SPD_*100];
  const int it = threadIdx.x / 10;
  const int jj = threadIdx.x - it*10;
  const bool act = threadIdx.x < 250;
  double a64[4][2] = {{0.0,0.0},{0.0,0.0},{0.0,0.0},{0.0,0.0}};
  for (int ch = 0; ch < 10; ++ch) {
    __syncthreads();
    const int tc0 = ch*100;
    for (int idx = threadIdx.x; idx < SPD_*100; idx += 256) {
      int row = idx / 100, tt = idx - row*100;
      xst[idx] = xc[((size_t)b*SPD_ + row)*T_ + tc0 + tt];
    }
    __syncthreads();
    if (act) {
      float a32[4][2] = {{0,0},{0,0},{0,0},{0,0}};
      for (int t4 = 0; t4 < 100; t4 += 4) {
        float4 xi[4], xj[2];
        #pragma unroll
        for (int r = 0; r < 4; ++r) xi[r] = *(const float4*)&xst[(it + 25*r)*100 + t4];
        #pragma unroll
        for (int s = 0; s < 2; ++s) xj[s] = *(const float4*)&xst[(j0 + jj + 10*s)*100 + t4];
        #pragma unroll
        for (int r = 0; r < 4; ++r)
          #pragma unroll
          for (int s = 0; s < 2; ++s)
            a32[r][s] += xi[r].x*xj[s].x + xi[r].y*xj[s].y + xi[r].z*xj[s].z + xi[r].w*xj[s].w;
      }
      #pragma unroll
      for (int r = 0; r < 4; ++r)
        #pragma unroll
        for (int s = 0; s < 2; ++s) a64[r][s] += (double)a32[r][s];
    }
  }
  if (act) {
    #pragma unroll
    for (int r = 0; r < 4; ++r) {
      #pragma unroll
      for (int s = 0; s < 2; ++s) {
        int i = it + 25*r, j = j0 + jj + 10*s;
        double v = a64[r][s] * (1.0/999.0);
        if (i == j) v += 1e-4;
        cov[(size_t)b*SPD_*SPD_ + i*SPD_ + j] = (float)v;
      }
    }
  }
}

// ---------------------------------------------------------------------------
// K4b: T1 = C @ W^T
// ---------------------------------------------------------------------------
__global__ __launch_bounds__(256) void k_aff1(const float* __restrict__ cov,
                                              const float* __restrict__ waff,
                                              float* __restrict__ T1) {
  const int b  = blockIdx.x / 5;
  const int j0 = (blockIdx.x % 5) * 20;
  __shared__ float Cs[SPD_*101];
  __shared__ float Ws[20*100];
  for (int idx = threadIdx.x; idx < SPD_*SPD_; idx += 256) {
    int r = idx / 100, c = idx - r*100;
    Cs[r*101 + c] = cov[(size_t)b*SPD_*SPD_ + idx];
  }
  for (int idx = threadIdx.x; idx < 2000; idx += 256) {
    int jl = idx / 100, k = idx - jl*100;
    Ws[idx] = waff[(j0+jl)*100 + k];
  }
  __syncthreads();
  if (threadIdx.x < 250) {
    const int it = threadIdx.x / 10, jj = threadIdx.x % 10;
    double acc[4][2] = {{0.0,0.0},{0.0,0.0},{0.0,0.0},{0.0,0.0}};
    for (int k = 0; k < 100; ++k) {
      double cvv[4], wv[2];
      #pragma unroll
      for (int r = 0; r < 4; ++r) cvv[r] = (double)Cs[(it + 25*r)*101 + k];
      #pragma unroll
      for (int s = 0; s < 2; ++s) wv[s] = (double)Ws[(jj + 10*s)*100 + k];
      #pragma unroll
      for (int r = 0; r < 4; ++r)
        #pragma unroll
        for (int s = 0; s < 2; ++s) acc[r][s] += cvv[r]*wv[s];
    }
    #pragma unroll
    for (int r = 0; r < 4; ++r)
      #pragma unroll
      for (int s = 0; s < 2; ++s)
        T1[(size_t)b*SPD_*SPD_ + (it + 25*r)*100 + (j0 + jj + 10*s)] = (float)acc[r][s];
  }
}

// ---------------------------------------------------------------------------
// K4c: P = W @ T1
// ---------------------------------------------------------------------------
__global__ __launch_bounds__(256) void k_aff2(const float* __restrict__ T1,
                                              const float* __restrict__ waff,
                                              float* __restrict__ P) {
  const int b  = blockIdx.x / 5;
  const int j0 = (blockIdx.x % 5) * 20;
  __shared__ float T1s[100*20];
  for (int idx = threadIdx.x; idx < 2000; idx += 256) {
    int k = idx / 20, jl = idx - k*20;
    T1s[idx] = T1[(size_t)b*SPD_*SPD_ + k*100 + j0 + jl];
  }
  __syncthreads();
  if (threadIdx.x < 250) {
    const int it = threadIdx.x / 10, jj = threadIdx.x % 10;
    double acc[4][2] = {{0.0,0.0},{0.0,0.0},{0.0,0.0},{0.0,0.0}};
    for (int k = 0; k < 100; ++k) {
      double wv[4], tv[2];
      #pragma unroll
      for (int r = 0; r < 4; ++r) wv[r] = (double)waff[(it + 25*r)*100 + k];
      #pragma unroll
      for (int s = 0; s < 2; ++s) tv[s] = (double)T1s[k*20 + jj + 10*s];
      #pragma unroll
      for (int r = 0; r < 4; ++r)
        #pragma unroll
        for (int s = 0; s < 2; ++s) acc[r][s] += wv[r]*tv[s];
    }
    #pragma unroll
    for (int r = 0; r < 4; ++r)
      #pragma unroll
      for (int s = 0; s < 2; ++s)
        P[(size_t)b*SPD_*SPD_ + (it + 25*r)*100 + (j0 + jj + 10*s)] = (float)acc[r][s];
  }
}

// ---------------------------------------------------------------------------
// K5: one-sided Jacobi eig, fp32, 4 lanes/pair, registers carry columns from
// dot-phase to rotate-phase (pairs disjoint => safe), 1 barrier/round.
// ---------------------------------------------------------------------------
__global__ __launch_bounds__(256) void k_eig(const float* __restrict__ P, float* __restrict__ out) {
  __shared__ __align__(16) float G[SPD_*LDSTR];
  __shared__ float dn[SPD_];
  __shared__ double wc[SPD_];
  __shared__ int flag;
  const int tid = threadIdx.x;
  const int b = blockIdx.x;

  // load: column c of G = row c of P (P symmetric)
  for (int idx = tid; idx < SPD_*SPD_; idx += 256) {
    int c = idx / SPD_, i = idx - c*SPD_;
    G[c*LDSTR + i] = P[b*SPD_*SPD_ + idx];
  }
  if (tid == 0) flag = 0;
  __syncthreads();
  if (tid < SPD_) {
    const float* col = &G[tid*LDSTR];
    float s = 0.f;
    for (int i = 0; i < SPD_; ++i) { float v = col[i]; s += v*v; }
    dn[tid] = s;
  }
  __syncthreads();

  const int jg = tid >> 2;     // pair group 0..63 (50 active)
  const int l4 = tid & 3;
  const bool act = (jg < 50);

  for (int sweep = 0; sweep < 14; ++sweep) {
    for (int r = 0; r < 99; ++r) {
      int p, q;
      if (jg == 0) {
        p = 99;
        q = r + 98; if (q >= 99) q -= 99;
      } else {
        p = r + jg - 1;  if (p >= 99) p -= 99;
        q = r + 98 - jg; if (q >= 99) q -= 99;
      }
      float4 pr[7], qr[7];
      float gamma = 0.f;
      const float4* cp = (const float4*)&G[p*LDSTR];
      const float4* cq = (const float4*)&G[q*LDSTR];
      if (act) {
        #pragma unroll
        for (int k = 0; k < 7; ++k) {
          int e = l4 + 4*k;
          if (e < 25) {
            pr[k] = cp[e]; qr[k] = cq[e];
            gamma += pr[k].x*qr[k].x + pr[k].y*qr[k].y + pr[k].z*qr[k].z + pr[k].w*qr[k].w;
          }
        }
      }
      gamma += __shfl_down(gamma, 2, 4);
      gamma += __shfl_down(gamma, 1, 4);
      float cr = 1.f, sr = 0.f;
      int rot = 0;
      if (act && l4 == 0) {
        float alpha = dn[p], beta = dn[q];
        float g2 = gamma * gamma;
        float ab = alpha * beta;
        if (g2 > 1e-12f * ab) {          // rotate if |g| > 1e-6*sqrt(ab)
          rot = 1;
          if (g2 > 1e-10f * ab) flag = 1; // keep sweeping if |g| > 1e-5*sqrt(ab)
          float tau = (beta - alpha) / (2.f * gamma);
          float t = ((tau >= 0.f) ? 1.f : -1.f) / (fabsf(tau) + sqrtf(1.f + tau*tau));
          cr = rsqrtf(1.f + t*t);
          sr = t * cr;
          dn[p] = alpha - t*gamma;
          dn[q] = beta  + t*gamma;
        }
      }
      rot = __shfl(rot, 0, 4);
      cr  = __shfl(cr, 0, 4);
      sr  = __shfl(sr, 0, 4);
      if (act && rot) {
        float4* wp = (float4*)&G[p*LDSTR];
        float4* wq = (float4*)&G[q*LDSTR];
        #pragma unroll
        for (int k = 0; k < 7; ++k) {
          int e = l4 + 4*k;
          if (e < 25) {
            float4 a, bb;
            a.x  = cr*pr[k].x - sr*qr[k].x;
            a.y  = cr*pr[k].y - sr*qr[k].y;
            a.z  = cr*pr[k].z - sr*qr[k].z;
            a.w  = cr*pr[k].w - sr*qr[k].w;
            bb.x = sr*pr[k].x + cr*qr[k].x;
            bb.y = sr*pr[k].y + cr*qr[k].y;
            bb.z = sr*pr[k].z + cr*qr[k].z;
            bb.w = sr*pr[k].w + cr*qr[k].w;
            wp[e] = a; wq[e] = bb;
          }
        }
      }
      __syncthreads();   // G writes visible before next round's re-pairing
    }
    int f = flag;
    __syncthreads();
    if (f == 0) break;
    if (tid == 0) flag = 0;
    __syncthreads();
  }

  // eigenvalues from fresh column norms (fp64); wc = log(clip(lam,1e-6))/lam^2
  if (tid < SPD_) {
    const float* col = &G[tid*LDSTR];
    double s = 0.0;
    for (int i = 0; i < SPD_; ++i) { double v = (double)col[i]; s += v*v; }
    double lam = sqrt(s);
    double lc  = (lam < 1e-6) ? 1e-6 : lam;
    wc[tid] = log(lc) / ((s > 1e-300) ? s : 1e-300);
  }
  __syncthreads();

  // L = sum_c wc[c] * g_c g_c^T ; scaled upper-tri -> out[64 + b*5050 + idx]
  for (int tile = tid; tile < 625; tile += 256) {
    const int ti = (tile / 25) * 4;
    const int tj = (tile % 25) * 4;
    float acc[4][4];
    #pragma unroll
    for (int r = 0; r < 4; ++r)
      #pragma unroll
      for (int s = 0; s < 4; ++s) acc[r][s] = 0.f;
    for (int c = 0; c < SPD_; ++c) {
      const float* col = &G[c*LDSTR];
      float4 ga = *(const float4*)&col[ti];
      float4 gb = *(const float4*)&col[tj];
      float w = (float)wc[c];
      float wa[4] = { w*ga.x, w*ga.y, w*ga.z, w*ga.w };
      float bv[4] = { gb.x, gb.y, gb.z, gb.w };
      #pragma unroll
      for (int r = 0; r < 4; ++r)
        #pragma unroll
        for (int s = 0; s < 4; ++s) acc[r][s] += wa[r]*bv[s];
    }
    const float RT2 = 1.41421356237309505f;
    #pragma unroll
    for (int r = 0; r < 4; ++r) {
      #pragma unroll
      for (int s = 0; s < 4; ++s) {
        int i = ti + r, j = tj + s;
        if (i <= j) {
          int idx = i*SPD_ - (i*(i+1))/2 + j;
          out[64 + b*5050 + idx] = acc[r][s] * (i == j ? 1.f : RT2);
        }
      }
    }
  }
}

// ---------------------------------------------------------------------------
// K6: logits = flat @ w_fc^T + b_fc
// ---------------------------------------------------------------------------
__global__ __launch_bounds__(256) void k_fc(const float* __restrict__ wfc,
                                            const float* __restrict__ bfc,
                                            float* __restrict__ out) {
  __shared__ float red[8];
  const int b = blockIdx.x;
  const float* flat = out + 64 + b*5050;
  float a0 = 0.f, a1 = 0.f, a2 = 0.f, a3 = 0.f;
  for (int k = threadIdx.x; k < 5050; k += 256) {
    float f = flat[k];
    a0 += f * wfc[k];
    a1 += f * wfc[5050 + k];
    a2 += f * wfc[10100 + k];
    a3 += f * wfc[15150 + k];
  }
  a0 = block_sum(a0, red);
  a1 = block_sum(a1, red);
  a2 = block_sum(a2, red);
  a3 = block_sum(a3, red);
  if (threadIdx.x == 0) {
    out[b*4 + 0] = a0 + bfc[0];
    out[b*4 + 1] = a1 + bfc[1];
    out[b*4 + 2] = a2 + bfc[2];
    out[b*4 + 3] = a3 + bfc[3];
  }
}

extern "C" void kernel_launch(void* const* d_in, const int* in_sizes, int n_in,
                              void* d_out, int out_size, void* d_ws, size_t ws_size,
                              hipStream_t stream) {
  (void)in_sizes; (void)n_in; (void)out_size; (void)ws_size;
  const float* x = (const float*)d_in[0];
  const float* bw[3][9];
  for (int i = 0; i < 3; ++i)
    for (int j = 0; j < 9; ++j)
      bw[i][j] = (const float*)d_in[1 + i*9 + j];
  const float* w_sconv = (const float*)d_in[28];
  const float* w_aff   = (const float*)d_in[29];
  const float* w_fc    = (const float*)d_in[30];
  const float* b_fc    = (const float*)d_in[31];

  char* ws = (char*)d_ws;
  float* M2   = (float*)(ws + OFF_M2);
  float* hcat = (float*)(ws + OFF_HCAT);
  float* xc   = (float*)(ws + OFF_XC);
  float* cov  = (float*)(ws + OFF_COV);
  float* T1   = (float*)(ws + OFF_T1);
  float* P    = (float*)(ws + OFF_P);
  float* out  = (float*)d_out;

  PrepPtrs pp; FrontPtrs fp;
  for (int i = 0; i < 3; ++i) {
    pp.w1[i] = bw[i][0]; pp.w2[i] = bw[i][1]; pp.w3[i] = bw[i][2]; pp.w4[i] = bw[i][3];
    fp.g1[i] = bw[i][4]; fp.b1[i] = bw[i][5]; fp.w5[i] = bw[i][6];
    fp.g2[i] = bw[i][7]; fp.b2[i] = bw[i][8];
  }
  fp.K[0] = 15; fp.K[1] = 75; fp.K[2] = 55;

  hipLaunchKernelGGL(k_prep,  dim3(3),            dim3(256), 0, stream, pp, M2);
  hipLaunchKernelGGL(k_front, dim3(3*B_*FCH_),    dim3(256), 0, stream, x, M2, fp, hcat);
  hipLaunchKernelGGL(k_sconv, dim3(B_*10),        dim3(256), 0, stream, hcat, w_sconv, xc);
  hipLaunchKernelGGL(k_cov,   dim3(B_*5),         dim3(256), 0, stream, xc, cov);
  hipLaunchKernelGGL(k_aff1,  dim3(B_*5),         dim3(256), 0, stream, cov, w_aff, T1);
  hipLaunchKernelGGL(k_aff2,  dim3(B_*5),         dim3(256), 0, stream, T1, w_aff, P);
  hipLaunchKernelGGL(k_eig,   dim3(B_),           dim3(256), 0, stream, P, out);
  hipLaunchKernelGGL(k_fc,    dim3(B_),           dim3(256), 0, stream, w_fc, b_fc, out);
}